// Round 7
// baseline (283.030 us; speedup 1.0000x reference)
//
#include <hip/hip_runtime.h>

typedef unsigned int u32;
typedef unsigned long long u64;

// ---------------- problem constants ----------------
#define NCLS 80
#define NIMG 8
#define PRE_K 1000
#define POST_K 100
// HW: 15200, 3800, 950 ; strides 8,16,32 ; concat bases 0,15200,19000
#define SCTR_STRIDE 19952
#define PBUF_N 2048

__device__ __forceinline__ int HWof(int l){ return l==0?15200:(l==1?3800:950); }
__device__ __forceinline__ float STRof(int l){ return l==0?8.f:(l==1?16.f:32.f); }
// pool caps / per-image offsets (u64 indices); stride per img = 131072 keys
__device__ __forceinline__ u32 CAPof(int l){ return l==0?65536u:32768u; }
__device__ __forceinline__ u32 POFFof(int l){ return l==0?0u:(l==1?65536u:98304u); }

struct Ptrs {
  const float* logits[3];
  const float* reg[3];
  const float* ctr[3];
  const float* cofs[3];
  const float* locs[3];
};

// grid split: 149 lvl0-tiles, 38 lvl1, 10 lvl2 (2048 float4 per tile)
#define NB0 149
#define NB1 38
#define NBALL 197

// ---------------- workspace layout (bytes) ----------------
// zeroed every launch:
#define OFF_HIST1 0u            // 24*512*4 = 49152 (fallback only)
#define OFF_CAND  49152u        // 24*4
#define OFF_PCNT  49248u        // 24*4
#define OFF_THR   49344u        // 24*8*4 = 768 {B1, cntAbove, T22, n_l, ok, -,-,-}
#define OFF_MCNT  50112u        // 32
#define ZERO_BYTES 50144u
// not zeroed:
#define OFF_SCTR  50176u        // 8*19952*4 = 638464
#define OFF_POOL  688640u       // 8*131072*8 = 8388608
#define OFF_SORT  9077248u      // 24*1024*8 = 196608
#define OFF_MERG  9273856u      // 8*3072*8*4 = 786432  (total ~10.06 MB)

__device__ __forceinline__ float sigmoidf(float x){ return 1.0f/(1.0f+expf(-x)); }

// ---------------- K0: sigmoid(ctr) for all (img, concat-loc) ----------------
__global__ void sctr_kernel(Ptrs p, float* sctr){
  int img = blockIdx.y;
  int i = blockIdx.x*256 + threadIdx.x;
  if (i >= 19950) return;
  int l, loc;
  if (i < 15200){ l=0; loc=i; }
  else if (i < 19000){ l=1; loc=i-15200; }
  else { l=2; loc=i-19000; }
  int HW = HWof(l);
  float x = p.ctr[l][(size_t)img*HW + loc];
  sctr[img*SCTR_STRIDE + i] = sigmoidf(x);
}

// ---------------- streaming pass body -----------------------------------
// Computes scores; REFILL=false: counts candidates + pushes keys with coarse
// bin (bits>>21) >= static G[lvl]; REFILL=true: pushes keys with bin >= B1.
// Pushes staged in an LDS buffer; one global atomic per block (plus rare spill).
template<int LVL, bool REFILL>
__device__ __forceinline__ void pass_body(int tile, int img, const Ptrs& p, const float* sctr,
                                          u32* cand, u32* pcnt, const u32* thr, u64* pool,
                                          u64* pbuf, u32* shctl){
  constexpr int HW   = LVL==0?15200:(LVL==1?3800:950);
  constexpr int BASE = LVL==0?0:(LVL==1?15200:19000);
  constexpr int NE   = 80*HW;
  constexpr int NF4  = NE/4;
  const u32 CAP = CAPof(LVL);
  const int pair = img*3 + LVL;
  const size_t poff = (size_t)img*131072u + POFFof(LVL);
  // static floors: score >= {0.3125, 0.25, 0.125}
  const u32 tbin = REFILL ? thr[pair*8+0] : (LVL==0?501u:(LVL==1?500u:496u));
  const float4* plane = (const float4*)(p.logits[LVL] + (size_t)img*NE);
  const float* sc = sctr + img*SCTR_STRIDE + BASE;
  if (threadIdx.x==0){ shctl[0]=0; shctl[1]=0; }
  __syncthreads();
  u32 mc = 0;
  #pragma unroll
  for (int k=0;k<8;++k){
    int f4 = tile*2048 + k*256 + (int)threadIdx.x;
    if (f4 < NF4){
      float4 v = plane[f4];
      int e0 = f4*4;
      int cls0 = e0 / HW;
      int loc0 = e0 - cls0*HW;
      float ss[4];
      if (LVL==2){                        // HW=950 not %4: rows can split a float4
        #pragma unroll
        for (int j=0;j<4;++j){ int e=e0+j; int c=e/HW; ss[j]=sc[e-c*HW]; }
      } else {
        float4 s4 = *(const float4*)(sc + loc0);
        ss[0]=s4.x; ss[1]=s4.y; ss[2]=s4.z; ss[3]=s4.w;
      }
      float vv[4] = {v.x,v.y,v.z,v.w};
      #pragma unroll
      for (int j=0;j<4;++j){
        float sl = sigmoidf(vv[j]);
        if (sl > 0.05f){
          if (!REFILL) mc++;
          u32 bits = __float_as_uint(sl * ss[j]);
          if ((bits>>21) >= tbin){
            int e = e0 + j, cls, loc;
            if (LVL==2){ cls=e/HW; loc=e-cls*HW; } else { cls=cls0; loc=loc0+j; }
            u64 key = ((u64)bits<<32) | (u64)(0xFFFFFFFFu - (u32)(loc*NCLS + cls));
            u32 id = atomicAdd(&shctl[0], 1u);
            if (id < (u32)PBUF_N) pbuf[id] = key;
            else { u32 g = atomicAdd(&pcnt[pair],1u); if (g<CAP) pool[poff+g]=key; }
          }
        }
      }
    }
  }
  if (!REFILL && mc) atomicAdd(&shctl[1], mc);
  __syncthreads();
  u32 m = shctl[0]; if (m > (u32)PBUF_N) m = PBUF_N;
  if (threadIdx.x==0){
    if (m) shctl[2] = atomicAdd(&pcnt[pair], m);
    if (!REFILL && shctl[1]) atomicAdd(&cand[pair], shctl[1]);
  }
  __syncthreads();
  for (u32 i=threadIdx.x; i<m; i+=256){
    u32 d = shctl[2] + i;
    if (d < CAP) pool[poff+d] = pbuf[i];
  }
}

// ---------------- K1: THE single full-data pass ----------------
__global__ __launch_bounds__(256)
void fused_pass(Ptrs p, const float* sctr, u32* cand, u32* pcnt, u64* pool){
  __shared__ u64 pbuf[PBUF_N];
  __shared__ u32 shctl[4];
  const int bx=(int)blockIdx.x, img=(int)blockIdx.y;
  if (bx<NB0)          pass_body<0,false>(bx,        img,p,sctr,cand,pcnt,nullptr,pool,pbuf,shctl);
  else if (bx<NB0+NB1) pass_body<1,false>(bx-NB0,    img,p,sctr,cand,pcnt,nullptr,pool,pbuf,shctl);
  else                 pass_body<2,false>(bx-NB0-NB1,img,p,sctr,cand,pcnt,nullptr,pool,pbuf,shctl);
}

// ---------------- fallback: full coarse hist (only if pool insufficient) -----
template<int LVL>
__device__ __forceinline__ void fbhist_body(int tile, int img, const Ptrs& p,
                                            const float* sctr, u32* lh){
  constexpr int HW   = LVL==0?15200:(LVL==1?3800:950);
  constexpr int BASE = LVL==0?0:(LVL==1?15200:19000);
  constexpr int NE   = 80*HW;
  constexpr int NF4  = NE/4;
  const float4* plane = (const float4*)(p.logits[LVL] + (size_t)img*NE);
  const float* sc = sctr + img*SCTR_STRIDE + BASE;
  #pragma unroll
  for (int k=0;k<8;++k){
    int f4 = tile*2048 + k*256 + (int)threadIdx.x;
    if (f4 < NF4){
      float4 v = plane[f4];
      int e0 = f4*4;
      int cls0 = e0 / HW;
      int loc0 = e0 - cls0*HW;
      float ss[4];
      if (LVL==2){
        #pragma unroll
        for (int j=0;j<4;++j){ int e=e0+j; int c=e/HW; ss[j]=sc[e-c*HW]; }
      } else {
        float4 s4 = *(const float4*)(sc + loc0);
        ss[0]=s4.x; ss[1]=s4.y; ss[2]=s4.z; ss[3]=s4.w;
      }
      float vv[4] = {v.x,v.y,v.z,v.w};
      #pragma unroll
      for (int j=0;j<4;++j){
        float sl = sigmoidf(vv[j]);
        if (sl > 0.05f){
          u32 bits = __float_as_uint(sl * ss[j]);
          atomicAdd(&lh[bits>>21], 1u);
        }
      }
    }
  }
}

__global__ __launch_bounds__(256)
void fb_hist(Ptrs p, const float* sctr, const u32* cand, const u32* pcnt, u32* hist1){
  __shared__ u32 lh[512];
  const int bx=(int)blockIdx.x, img=(int)blockIdx.y;
  const int lvl = bx<NB0?0:(bx<NB0+NB1?1:2);
  const int pair = img*3+lvl;
  u32 pc = pcnt[pair], kk = min(cand[pair], (u32)PRE_K);
  if (pc <= CAPof(lvl) && pc >= kk) return;     // pool sufficient -> no fallback
  for (int b=threadIdx.x;b<512;b+=256) lh[b]=0;
  __syncthreads();
  if (lvl==0)      fbhist_body<0>(bx,        img,p,sctr,lh);
  else if (lvl==1) fbhist_body<1>(bx-NB0,    img,p,sctr,lh);
  else             fbhist_body<2>(bx-NB0-NB1,img,p,sctr,lh);
  __syncthreads();
  for (int b=threadIdx.x;b<512;b+=256) if (lh[b]) atomicAdd(&hist1[pair*512+b], lh[b]);
}

// ---------------- K2: coarse select (hist from pool OR fallback hist) + scan --
__global__ __launch_bounds__(256)
void selA(const u32* cand, u32* pcnt, u32* thr, const u32* hist1, const u64* pool){
  const int pair=(int)blockIdx.x, lvl=pair%3, img=pair/3;
  __shared__ u32 h[512], seg[256], excl[256];
  const u32 cap = CAPof(lvl);
  const size_t poff = (size_t)img*131072u + POFFof(lvl);
  u32 pc = pcnt[pair];
  u32 kk = min(cand[pair], (u32)PRE_K);
  bool ok = (pc <= cap) && (pc >= kk);
  for (int b=threadIdx.x;b<512;b+=256) h[b] = ok ? 0u : hist1[pair*512+b];
  __syncthreads();
  if (ok){
    for (u32 i=threadIdx.x; i<pc; i+=256)
      atomicAdd(&h[(u32)(pool[poff+i]>>53)], 1u);
  }
  __syncthreads();
  if (threadIdx.x==0){
    thr[pair*8+3] = kk;
    thr[pair*8+4] = ok ? 1u : 0u;
    if (!ok) pcnt[pair] = 0;                    // refill_pass will repopulate
    if (kk==0){ thr[pair*8+0]=0xFFFFu; thr[pair*8+2]=0xFFFFFFFFu; }
  }
  if (kk==0) return;
  // descending scan over 512 bins (2 per thread)
  const int t = threadIdx.x;
  u32 part = h[511-2*t] + h[511-(2*t+1)];
  seg[t]=part;
  __syncthreads();
  if (t==0){ u32 run=0; for (int i=0;i<256;++i){ excl[i]=run; run+=seg[i]; } }
  __syncthreads();
  u32 cum = excl[t];
  #pragma unroll
  for (int k=0;k<2;++k){
    int bin = 511-(2*t+k);
    u32 c = h[bin];
    if (c && cum < kk && cum + c >= kk){ thr[pair*8+0]=(u32)bin; thr[pair*8+1]=cum; }
    cum += c;
  }
}

// ---------------- fallback: exact refill of pool with bin >= B1 --------------
__global__ __launch_bounds__(256)
void refill_pass(Ptrs p, const float* sctr, u32* cand, u32* pcnt, const u32* thr, u64* pool){
  __shared__ u64 pbuf[PBUF_N];
  __shared__ u32 shctl[4];
  const int bx=(int)blockIdx.x, img=(int)blockIdx.y;
  const int lvl = bx<NB0?0:(bx<NB0+NB1?1:2);
  if (thr[(img*3+lvl)*8+4]) return;             // pool was sufficient
  if (lvl==0)      pass_body<0,true>(bx,        img,p,sctr,cand,pcnt,thr,pool,pbuf,shctl);
  else if (lvl==1) pass_body<1,true>(bx-NB0,    img,p,sctr,cand,pcnt,thr,pool,pbuf,shctl);
  else             pass_body<2,true>(bx-NB0-NB1,img,p,sctr,cand,pcnt,thr,pool,pbuf,shctl);
}

// ---------------- K3: fine select within boundary bin (from pool) + scan -----
__global__ __launch_bounds__(256)
void selB(u32* thr, const u32* pcnt, const u64* pool){
  const int pair=(int)blockIdx.x, lvl=pair%3, img=pair/3;
  const u32 kk = thr[pair*8+3];
  if (kk==0) return;                            // T22 already 0xFFFFFFFF
  const u32 B1 = thr[pair*8+0];
  const u32 KK = kk - thr[pair*8+1];            // remaining within boundary bin
  __shared__ u32 h[2048], seg[256], excl[256];
  for (int b=threadIdx.x;b<2048;b+=256) h[b]=0;
  __syncthreads();
  const size_t poff = (size_t)img*131072u + POFFof(lvl);
  const u32 pc = min(pcnt[pair], CAPof(lvl));
  for (u32 i=threadIdx.x; i<pc; i+=256){
    u64 key = pool[poff+i];
    if ((u32)(key>>53) == B1) atomicAdd(&h[(u32)(key>>42)&0x7FFu], 1u);
  }
  __syncthreads();
  const int t = threadIdx.x;
  u32 part = 0;
  #pragma unroll
  for (int k=0;k<8;++k) part += h[2047-(t*8+k)];
  seg[t]=part;
  __syncthreads();
  if (t==0){ u32 run=0; for (int i=0;i<256;++i){ excl[i]=run; run+=seg[i]; } }
  __syncthreads();
  u32 cum = excl[t];
  #pragma unroll
  for (int k=0;k<8;++k){
    int bin = 2047-(t*8+k);
    u32 c = h[bin];
    if (c && cum < KK && cum + c >= KK) thr[pair*8+2] = (B1<<11) | (u32)bin;
    cum += c;
  }
}

// ---------------- K4: gather accepted keys from pool, bitonic sort, top n_l --
__global__ __launch_bounds__(1024)
void sort_pool(u32* thr, const u32* pcnt, const u64* pool, u64* sorted){
  const int pair=(int)blockIdx.x, lvl=pair%3, img=pair/3;
  __shared__ u64 a[2048];
  __shared__ u32 cnt;
  for (int i=threadIdx.x;i<2048;i+=1024) a[i]=0ull;
  if (threadIdx.x==0) cnt=0;
  __syncthreads();
  const u32 T22 = thr[pair*8+2];
  const size_t poff = (size_t)img*131072u + POFFof(lvl);
  const u32 pc = min(pcnt[pair], CAPof(lvl));
  for (u32 i=threadIdx.x; i<pc; i+=1024){
    u64 k = pool[poff+i];
    if ((u32)(k>>42) >= T22){
      u32 id = atomicAdd(&cnt,1u);
      if (id < 2048u) a[id]=k;
    }
  }
  __syncthreads();
  const u32 n = min(cnt, 2048u);
  for (int k=2;k<=2048;k<<=1){
    for (int j=k>>1;j>0;j>>=1){
      for (int t=threadIdx.x;t<2048;t+=1024){
        int ix = t ^ j;
        if (ix > t){
          u64 x=a[t], y=a[ix];
          bool up = ((t & k)==0);
          if (up ? (x<y) : (x>y)){ a[t]=y; a[ix]=x; }
        }
      }
      __syncthreads();
    }
  }
  u32 KK = thr[pair*8+3];
  u32 m = KK < n ? KK : n;
  for (u32 r=threadIdx.x;r<m;r+=1024) sorted[(size_t)pair*1024+r]=a[r];
  if (threadIdx.x==0) thr[pair*8+3]=m;
}

// ---------------- K5: 3-way stable merge + box decode ----------------
__global__ void merge_kernel(Ptrs p, const u32* thr, const u64* sorted,
                             float* merged, u32* mcnt){
#pragma clang fp contract(off)
  const int img = blockIdx.x;
  __shared__ u64 mk[3][1024];
  __shared__ int n[3];
  if (threadIdx.x < 3) n[threadIdx.x] = (int)thr[(img*3+threadIdx.x)*8+3];
  __syncthreads();
  const int n0=n[0], n1=n[1], n2=n[2];
  for (int idx=threadIdx.x; idx<3*1024; idx+=blockDim.x){
    int l = idx>>10, r = idx&1023;
    if (r < n[l]){
      u64 key = sorted[(size_t)(img*3+l)*1024 + r];
      mk[l][r] = (key & 0xFFFFFFFF00000000ull) |
                 (u64)(0xFFFFFFFFu - (u32)(l*PRE_K + r));  // concat-idx tie-break
    }
  }
  __syncthreads();
  const int T = n0+n1+n2;
  if (threadIdx.x==0) mcnt[img] = (u32)T;
  for (int t=threadIdx.x; t<T; t+=blockDim.x){
    int l, r;
    if (t < n0){ l=0; r=t; }
    else if (t < n0+n1){ l=1; r=t-n0; }
    else { l=2; r=t-n0-n1; }
    u64 x = mk[l][r];
    int pos = r;
    #pragma unroll
    for (int o=0;o<3;++o) if (o!=l){
      int lo=0, hi=n[o];
      while (lo<hi){ int m=(lo+hi)>>1; if (mk[o][m] > x) lo=m+1; else hi=m; }
      pos += lo;
    }
    u64 key = sorted[(size_t)(img*3+l)*1024 + r];
    u32 flat = 0xFFFFFFFFu - (u32)(key & 0xFFFFFFFFull);
    float score = __uint_as_float((u32)(key>>32));
    int HW = HWof(l);
    int loc = (int)(flat / (u32)NCLS);
    int cls = (int)(flat - (u32)loc*NCLS);
    float lx = p.locs[l][2*loc], ly = p.locs[l][2*loc+1];
    float st = STRof(l);
    const float* rg = p.reg[l] + (size_t)img*4*HW + loc;
    float r0 = rg[0]*st, r1 = rg[HW]*st, r2 = rg[2*(size_t)HW]*st, r3 = rg[3*(size_t)HW]*st;
    float x1 = fminf(fmaxf(lx - r0, 0.f), 1216.f);
    float y1 = fminf(fmaxf(ly - r1, 0.f),  800.f);
    float x2 = fminf(fmaxf(lx + r2, 0.f), 1216.f);
    float y2 = fminf(fmaxf(ly + r3, 0.f),  800.f);
    float* out = merged + (size_t)(img*3072 + pos)*8;
    out[0]=x1; out[1]=y1; out[2]=x2; out[3]=y2;
    out[4]=score; out[5]=(float)cls; out[6]=(float)l; out[7]=(float)loc;
  }
}

// ---------------- K6: greedy NMS — single-wave bitmask version ----------------
// Build: ob (offset boxes) + per-class membership bitmask + alive bitmask.
// Greedy (wave 0 only, no barriers): find-next via ballot over alive words;
// suppress by walking ONLY the kept box's class mask (cross-class IoU == 0
// by construction of the class offset). IoU expression identical to the
// twice-validated kernel (fp contract off).
__global__ __launch_bounds__(256)
void nms_kernel(Ptrs p, const float* merged_all, const u32* mcnt, float* out){
#pragma clang fp contract(off)
  const int img = blockIdx.x;
  const float* merged = merged_all + (size_t)img*3072*8;
  __shared__ float4 ob[3072];           // 48 KB
  __shared__ u64 cmask[NCLS][48];       // 30 KB per-class membership bits
  __shared__ u64 alive[48];
  __shared__ unsigned char clsb[3072];
  __shared__ unsigned short klist[128];
  __shared__ int skept;
  const int T = (int)mcnt[img];
  const int tid = (int)threadIdx.x;

  u64* cm = &cmask[0][0];
  for (int i=tid; i<NCLS*48; i+=256) cm[i] = 0ull;
  if (tid < 48){
    int lo = tid*64;
    u64 w;
    if (lo >= T) w = 0ull;
    else if (T - lo >= 64) w = ~0ull;
    else w = (1ull << (T - lo)) - 1ull;
    alive[tid] = w;
  }
  __syncthreads();
  for (int j=tid; j<T; j+=256){
    const float* rec = merged + (size_t)j*8;
    float off = rec[5]*1217.0f;               // replicate ref's rounded offset boxes
    ob[j] = make_float4(rec[0]+off, rec[1]+off, rec[2]+off, rec[3]+off);
    int c = (int)rec[5];
    clsb[j] = (unsigned char)c;
    atomicOr(&cmask[c][j>>6], 1ull << (j&63));
  }
  __syncthreads();

  if (tid < 64){
    int kept = 0;
    int cur = -1;
    volatile u64* va = alive;
    while (kept < POST_K){
      // ---- find first alive index > cur ----
      u64 m = 0;
      if (tid < 48){
        m = va[tid];
        int cw = cur >> 6;                     // cur==-1 -> cw==-1, no masking
        if (tid < cw) m = 0;
        else if (tid == cw){
          int b = cur & 63;
          m &= (b==63) ? 0ull : ~((1ull<<(b+1))-1ull);
        }
      }
      u64 bal = __ballot(m != 0);
      if (bal == 0) break;
      int wsel = __ffsll((unsigned long long)bal) - 1;
      u64 wm = __shfl(m, wsel);
      int i = wsel*64 + __ffsll((unsigned long long)wm) - 1;
      if (tid==0) klist[kept] = (unsigned short)i;
      kept++;
      cur = i;
      if (kept >= POST_K) break;
      // ---- suppress same-class boxes j > i ----
      float4 bi = ob[i];                       // broadcast
      int ci = clsb[i];
      float ai = (bi.z-bi.x)*(bi.w-bi.y);
      if (tid < 48){
        u64 mm = cmask[ci][tid];
        int cw = i >> 6;
        if (tid < cw) mm = 0;
        else if (tid == cw){
          int b = i & 63;
          mm &= (b==63) ? 0ull : ~((1ull<<(b+1))-1ull);
        }
        u64 kill = 0;
        while (mm){
          int b = __ffsll((unsigned long long)mm) - 1;
          mm &= mm - 1ull;
          int j = tid*64 + b;
          float4 bj = ob[j];
          float aj = (bj.z-bj.x)*(bj.w-bj.y);
          float ltx = fmaxf(bi.x,bj.x), lty = fmaxf(bi.y,bj.y);
          float rbx = fminf(bi.z,bj.z), rby = fminf(bi.w,bj.w);
          float wx = fmaxf(rbx-ltx, 0.f), wy = fmaxf(rby-lty, 0.f);
          float inter = wx*wy;
          float denom = ai + aj;
          denom = denom - inter;
          denom = denom + 1e-9f;
          if (inter/denom > 0.6f) kill |= (1ull << b);
        }
        if (kill) atomicAnd((unsigned long long*)&alive[tid], ~kill);
      }
      __threadfence_block();
    }
    if (tid==0) skept = kept;
  }
  __syncthreads();
  const int kept = skept;

  // ---- outputs: boxes[8][100][4] | scores[8][100] | cls[8][100] | cofs[8][100][128] | kv[8][100]
  float* obx = out;
  float* osc = out + 3200;
  float* ocl = out + 4000;
  float* ocf = out + 4800;
  float* okv = out + 107200;
  for (int r=tid; r<POST_K; r+=256){
    if (r < kept){
      int i = klist[r];
      const float* rec = merged + (size_t)i*8;
      obx[(img*POST_K+r)*4+0]=rec[0];
      obx[(img*POST_K+r)*4+1]=rec[1];
      obx[(img*POST_K+r)*4+2]=rec[2];
      obx[(img*POST_K+r)*4+3]=rec[3];
      osc[img*POST_K+r] = sqrtf(fmaxf(rec[4], 1e-12f));
      ocl[img*POST_K+r] = rec[5];
      okv[img*POST_K+r] = 1.0f;
    } else {
      obx[(img*POST_K+r)*4+0]=0.f;
      obx[(img*POST_K+r)*4+1]=0.f;
      obx[(img*POST_K+r)*4+2]=0.f;
      obx[(img*POST_K+r)*4+3]=0.f;
      osc[img*POST_K+r] = 0.f;
      ocl[img*POST_K+r] = -1.0f;
      okv[img*POST_K+r] = 0.f;
    }
  }
  for (int q=tid; q<POST_K*128; q+=256){
    int r = q>>7, d = q&127;
    float v = 0.f;
    if (r < kept){
      int i = klist[r];
      const float* rec = merged + (size_t)i*8;
      int l = (int)rec[6]; int loc = (int)rec[7];
      int HW = HWof(l);
      v = p.cofs[l][((size_t)img*128 + d)*HW + loc];
    }
    ocf[(img*POST_K+r)*128 + d] = v;
  }
}

// ---------------- host ----------------
extern "C" void kernel_launch(void* const* d_in, const int* in_sizes, int n_in,
                              void* d_out, int out_size, void* d_ws, size_t ws_size,
                              hipStream_t stream){
  Ptrs p;
  for (int l=0; l<3; ++l){
    p.locs[l]   = (const float*)d_in[5*l+0];
    p.logits[l] = (const float*)d_in[5*l+1];
    p.reg[l]    = (const float*)d_in[5*l+2];
    p.ctr[l]    = (const float*)d_in[5*l+3];
    p.cofs[l]   = (const float*)d_in[5*l+4];
  }
  char* ws = (char*)d_ws;
  u32* hist1  = (u32*)(ws + OFF_HIST1);
  u32* cand   = (u32*)(ws + OFF_CAND);
  u32* pcnt   = (u32*)(ws + OFF_PCNT);
  u32* thr    = (u32*)(ws + OFF_THR);
  u32* mcnt   = (u32*)(ws + OFF_MCNT);
  float* sctr = (float*)(ws + OFF_SCTR);
  u64* pool   = (u64*)(ws + OFF_POOL);
  u64* sorted = (u64*)(ws + OFF_SORT);
  float* merged = (float*)(ws + OFF_MERG);

  hipMemsetAsync(ws, 0, ZERO_BYTES, stream);
  sctr_kernel<<<dim3(78,8), 256, 0, stream>>>(p, sctr);
  fused_pass<<<dim3(NBALL,8), 256, 0, stream>>>(p, sctr, cand, pcnt, pool);
  fb_hist<<<dim3(NBALL,8), 256, 0, stream>>>(p, sctr, cand, pcnt, hist1);     // no-op when pool suffices
  selA<<<24, 256, 0, stream>>>(cand, pcnt, thr, hist1, pool);
  refill_pass<<<dim3(NBALL,8), 256, 0, stream>>>(p, sctr, cand, pcnt, thr, pool); // no-op when pool suffices
  selB<<<24, 256, 0, stream>>>(thr, pcnt, pool);
  sort_pool<<<24, 1024, 0, stream>>>(thr, pcnt, pool, sorted);
  merge_kernel<<<8, 1024, 0, stream>>>(p, thr, sorted, merged, mcnt);
  nms_kernel<<<8, 256, 0, stream>>>(p, merged, mcnt, (float*)d_out);
}

// Round 8
// 233.005 us; speedup vs baseline: 1.2147x; 1.2147x over previous
//
#include <hip/hip_runtime.h>

typedef unsigned int u32;
typedef unsigned long long u64;

// ---------------- problem constants ----------------
#define NCLS 80
#define NIMG 8
#define PRE_K 1000
#define POST_K 100
// HW: 15200, 3800, 950 ; strides 8,16,32 ; concat bases 0,15200,19000
#define SCTR_STRIDE 19952
#define PBUF_N 2048

__device__ __forceinline__ int HWof(int l){ return l==0?15200:(l==1?3800:950); }
__device__ __forceinline__ float STRof(int l){ return l==0?8.f:(l==1?16.f:32.f); }
// pool caps / per-image offsets (u64 indices); stride per img = 131072 keys
__device__ __forceinline__ u32 CAPof(int l){ return l==0?65536u:32768u; }
__device__ __forceinline__ u32 POFFof(int l){ return l==0?0u:(l==1?65536u:98304u); }

struct Ptrs {
  const float* logits[3];
  const float* reg[3];
  const float* ctr[3];
  const float* cofs[3];
  const float* locs[3];
};

// grid split: 149 lvl0-tiles, 38 lvl1, 10 lvl2 (2048 float4 per tile)
#define NB0 149
#define NB1 38
#define NBALL 197

// ---------------- workspace layout (bytes) ----------------
// zeroed every launch:
#define OFF_HIST1 0u            // 24*512*4 = 49152 (fallback only)
#define OFF_CAND  49152u        // 24*4
#define OFF_PCNT  49248u        // 24*4
#define OFF_THR   49344u        // 24*8*4 = 768 {B1, cntAbove, T22, n_l, ok, -,-,-}
#define OFF_MCNT  50112u        // 32
#define OFF_KEEP  50144u        // 8*48*8 = 3072 keep bitmask per image
#define ZERO_BYTES 53216u
// not zeroed:
#define OFF_SCTR  53248u        // 8*19952*4 = 638464
#define OFF_POOL  691712u       // 8*131072*8 = 8388608  (dead after sort_pool;
                                //  first 98304B reused as clsarr by merge)
#define OFF_SORT  9080320u      // 24*1024*8 = 196608
#define OFF_MERG  9276928u      // 8*3072*8*4 = 786432   (total ~10.06 MB)

__device__ __forceinline__ float sigmoidf(float x){ return 1.0f/(1.0f+expf(-x)); }

// ---------------- K0: sigmoid(ctr) for all (img, concat-loc) ----------------
__global__ void sctr_kernel(Ptrs p, float* sctr){
  int img = blockIdx.y;
  int i = blockIdx.x*256 + threadIdx.x;
  if (i >= 19950) return;
  int l, loc;
  if (i < 15200){ l=0; loc=i; }
  else if (i < 19000){ l=1; loc=i-15200; }
  else { l=2; loc=i-19000; }
  int HW = HWof(l);
  float x = p.ctr[l][(size_t)img*HW + loc];
  sctr[img*SCTR_STRIDE + i] = sigmoidf(x);
}

// ---------------- streaming pass body -----------------------------------
template<int LVL, bool REFILL>
__device__ __forceinline__ void pass_body(int tile, int img, const Ptrs& p, const float* sctr,
                                          u32* cand, u32* pcnt, const u32* thr, u64* pool,
                                          u64* pbuf, u32* shctl){
  constexpr int HW   = LVL==0?15200:(LVL==1?3800:950);
  constexpr int BASE = LVL==0?0:(LVL==1?15200:19000);
  constexpr int NE   = 80*HW;
  constexpr int NF4  = NE/4;
  const u32 CAP = CAPof(LVL);
  const int pair = img*3 + LVL;
  const size_t poff = (size_t)img*131072u + POFFof(LVL);
  // static floors: score >= {0.3125, 0.25, 0.125}
  const u32 tbin = REFILL ? thr[pair*8+0] : (LVL==0?501u:(LVL==1?500u:496u));
  const float4* plane = (const float4*)(p.logits[LVL] + (size_t)img*NE);
  const float* sc = sctr + img*SCTR_STRIDE + BASE;
  if (threadIdx.x==0){ shctl[0]=0; shctl[1]=0; }
  __syncthreads();
  u32 mc = 0;
  #pragma unroll
  for (int k=0;k<8;++k){
    int f4 = tile*2048 + k*256 + (int)threadIdx.x;
    if (f4 < NF4){
      float4 v = plane[f4];
      int e0 = f4*4;
      int cls0 = e0 / HW;
      int loc0 = e0 - cls0*HW;
      float ss[4];
      if (LVL==2){                        // HW=950 not %4: rows can split a float4
        #pragma unroll
        for (int j=0;j<4;++j){ int e=e0+j; int c=e/HW; ss[j]=sc[e-c*HW]; }
      } else {
        float4 s4 = *(const float4*)(sc + loc0);
        ss[0]=s4.x; ss[1]=s4.y; ss[2]=s4.z; ss[3]=s4.w;
      }
      float vv[4] = {v.x,v.y,v.z,v.w};
      #pragma unroll
      for (int j=0;j<4;++j){
        float sl = sigmoidf(vv[j]);
        if (sl > 0.05f){
          if (!REFILL) mc++;
          u32 bits = __float_as_uint(sl * ss[j]);
          if ((bits>>21) >= tbin){
            int e = e0 + j, cls, loc;
            if (LVL==2){ cls=e/HW; loc=e-cls*HW; } else { cls=cls0; loc=loc0+j; }
            u64 key = ((u64)bits<<32) | (u64)(0xFFFFFFFFu - (u32)(loc*NCLS + cls));
            u32 id = atomicAdd(&shctl[0], 1u);
            if (id < (u32)PBUF_N) pbuf[id] = key;
            else { u32 g = atomicAdd(&pcnt[pair],1u); if (g<CAP) pool[poff+g]=key; }
          }
        }
      }
    }
  }
  if (!REFILL && mc) atomicAdd(&shctl[1], mc);
  __syncthreads();
  u32 m = shctl[0]; if (m > (u32)PBUF_N) m = PBUF_N;
  if (threadIdx.x==0){
    if (m) shctl[2] = atomicAdd(&pcnt[pair], m);
    if (!REFILL && shctl[1]) atomicAdd(&cand[pair], shctl[1]);
  }
  __syncthreads();
  for (u32 i=threadIdx.x; i<m; i+=256){
    u32 d = shctl[2] + i;
    if (d < CAP) pool[poff+d] = pbuf[i];
  }
}

// ---------------- K1: THE single full-data pass ----------------
__global__ __launch_bounds__(256)
void fused_pass(Ptrs p, const float* sctr, u32* cand, u32* pcnt, u64* pool){
  __shared__ u64 pbuf[PBUF_N];
  __shared__ u32 shctl[4];
  const int bx=(int)blockIdx.x, img=(int)blockIdx.y;
  if (bx<NB0)          pass_body<0,false>(bx,        img,p,sctr,cand,pcnt,nullptr,pool,pbuf,shctl);
  else if (bx<NB0+NB1) pass_body<1,false>(bx-NB0,    img,p,sctr,cand,pcnt,nullptr,pool,pbuf,shctl);
  else                 pass_body<2,false>(bx-NB0-NB1,img,p,sctr,cand,pcnt,nullptr,pool,pbuf,shctl);
}

// ---------------- fallback: full coarse hist (only if pool insufficient) -----
template<int LVL>
__device__ __forceinline__ void fbhist_body(int tile, int img, const Ptrs& p,
                                            const float* sctr, u32* lh){
  constexpr int HW   = LVL==0?15200:(LVL==1?3800:950);
  constexpr int BASE = LVL==0?0:(LVL==1?15200:19000);
  constexpr int NE   = 80*HW;
  constexpr int NF4  = NE/4;
  const float4* plane = (const float4*)(p.logits[LVL] + (size_t)img*NE);
  const float* sc = sctr + img*SCTR_STRIDE + BASE;
  #pragma unroll
  for (int k=0;k<8;++k){
    int f4 = tile*2048 + k*256 + (int)threadIdx.x;
    if (f4 < NF4){
      float4 v = plane[f4];
      int e0 = f4*4;
      int cls0 = e0 / HW;
      int loc0 = e0 - cls0*HW;
      float ss[4];
      if (LVL==2){
        #pragma unroll
        for (int j=0;j<4;++j){ int e=e0+j; int c=e/HW; ss[j]=sc[e-c*HW]; }
      } else {
        float4 s4 = *(const float4*)(sc + loc0);
        ss[0]=s4.x; ss[1]=s4.y; ss[2]=s4.z; ss[3]=s4.w;
      }
      float vv[4] = {v.x,v.y,v.z,v.w};
      #pragma unroll
      for (int j=0;j<4;++j){
        float sl = sigmoidf(vv[j]);
        if (sl > 0.05f){
          u32 bits = __float_as_uint(sl * ss[j]);
          atomicAdd(&lh[bits>>21], 1u);
        }
      }
    }
  }
}

__global__ __launch_bounds__(256)
void fb_hist(Ptrs p, const float* sctr, const u32* cand, const u32* pcnt, u32* hist1){
  __shared__ u32 lh[512];
  const int bx=(int)blockIdx.x, img=(int)blockIdx.y;
  const int lvl = bx<NB0?0:(bx<NB0+NB1?1:2);
  const int pair = img*3+lvl;
  u32 pc = pcnt[pair], kk = min(cand[pair], (u32)PRE_K);
  if (pc <= CAPof(lvl) && pc >= kk) return;     // pool sufficient -> no fallback
  for (int b=threadIdx.x;b<512;b+=256) lh[b]=0;
  __syncthreads();
  if (lvl==0)      fbhist_body<0>(bx,        img,p,sctr,lh);
  else if (lvl==1) fbhist_body<1>(bx-NB0,    img,p,sctr,lh);
  else             fbhist_body<2>(bx-NB0-NB1,img,p,sctr,lh);
  __syncthreads();
  for (int b=threadIdx.x;b<512;b+=256) if (lh[b]) atomicAdd(&hist1[pair*512+b], lh[b]);
}

// ---------------- K2: coarse select (hist from pool OR fallback hist) + scan --
__global__ __launch_bounds__(256)
void selA(const u32* cand, u32* pcnt, u32* thr, const u32* hist1, const u64* pool){
  const int pair=(int)blockIdx.x, lvl=pair%3, img=pair/3;
  __shared__ u32 h[512], seg[256], excl[256];
  const u32 cap = CAPof(lvl);
  const size_t poff = (size_t)img*131072u + POFFof(lvl);
  u32 pc = pcnt[pair];
  u32 kk = min(cand[pair], (u32)PRE_K);
  bool ok = (pc <= cap) && (pc >= kk);
  for (int b=threadIdx.x;b<512;b+=256) h[b] = ok ? 0u : hist1[pair*512+b];
  __syncthreads();
  if (ok){
    for (u32 i=threadIdx.x; i<pc; i+=256)
      atomicAdd(&h[(u32)(pool[poff+i]>>53)], 1u);
  }
  __syncthreads();
  if (threadIdx.x==0){
    thr[pair*8+3] = kk;
    thr[pair*8+4] = ok ? 1u : 0u;
    if (!ok) pcnt[pair] = 0;                    // refill_pass will repopulate
    if (kk==0){ thr[pair*8+0]=0xFFFFu; thr[pair*8+2]=0xFFFFFFFFu; }
  }
  if (kk==0) return;
  // descending scan over 512 bins (2 per thread)
  const int t = threadIdx.x;
  u32 part = h[511-2*t] + h[511-(2*t+1)];
  seg[t]=part;
  __syncthreads();
  if (t==0){ u32 run=0; for (int i=0;i<256;++i){ excl[i]=run; run+=seg[i]; } }
  __syncthreads();
  u32 cum = excl[t];
  #pragma unroll
  for (int k=0;k<2;++k){
    int bin = 511-(2*t+k);
    u32 c = h[bin];
    if (c && cum < kk && cum + c >= kk){ thr[pair*8+0]=(u32)bin; thr[pair*8+1]=cum; }
    cum += c;
  }
}

// ---------------- fallback: exact refill of pool with bin >= B1 --------------
__global__ __launch_bounds__(256)
void refill_pass(Ptrs p, const float* sctr, u32* cand, u32* pcnt, const u32* thr, u64* pool){
  __shared__ u64 pbuf[PBUF_N];
  __shared__ u32 shctl[4];
  const int bx=(int)blockIdx.x, img=(int)blockIdx.y;
  const int lvl = bx<NB0?0:(bx<NB0+NB1?1:2);
  if (thr[(img*3+lvl)*8+4]) return;             // pool was sufficient
  if (lvl==0)      pass_body<0,true>(bx,        img,p,sctr,cand,pcnt,thr,pool,pbuf,shctl);
  else if (lvl==1) pass_body<1,true>(bx-NB0,    img,p,sctr,cand,pcnt,thr,pool,pbuf,shctl);
  else             pass_body<2,true>(bx-NB0-NB1,img,p,sctr,cand,pcnt,thr,pool,pbuf,shctl);
}

// ---------------- K3: fine select within boundary bin (from pool) + scan -----
__global__ __launch_bounds__(256)
void selB(u32* thr, const u32* pcnt, const u64* pool){
  const int pair=(int)blockIdx.x, lvl=pair%3, img=pair/3;
  const u32 kk = thr[pair*8+3];
  if (kk==0) return;                            // T22 already 0xFFFFFFFF
  const u32 B1 = thr[pair*8+0];
  const u32 KK = kk - thr[pair*8+1];            // remaining within boundary bin
  __shared__ u32 h[2048], seg[256], excl[256];
  for (int b=threadIdx.x;b<2048;b+=256) h[b]=0;
  __syncthreads();
  const size_t poff = (size_t)img*131072u + POFFof(lvl);
  const u32 pc = min(pcnt[pair], CAPof(lvl));
  for (u32 i=threadIdx.x; i<pc; i+=256){
    u64 key = pool[poff+i];
    if ((u32)(key>>53) == B1) atomicAdd(&h[(u32)(key>>42)&0x7FFu], 1u);
  }
  __syncthreads();
  const int t = threadIdx.x;
  u32 part = 0;
  #pragma unroll
  for (int k=0;k<8;++k) part += h[2047-(t*8+k)];
  seg[t]=part;
  __syncthreads();
  if (t==0){ u32 run=0; for (int i=0;i<256;++i){ excl[i]=run; run+=seg[i]; } }
  __syncthreads();
  u32 cum = excl[t];
  #pragma unroll
  for (int k=0;k<8;++k){
    int bin = 2047-(t*8+k);
    u32 c = h[bin];
    if (c && cum < KK && cum + c >= KK) thr[pair*8+2] = (B1<<11) | (u32)bin;
    cum += c;
  }
}

// ---------------- K4: gather accepted keys from pool, bitonic sort, top n_l --
__global__ __launch_bounds__(1024)
void sort_pool(u32* thr, const u32* pcnt, const u64* pool, u64* sorted){
  const int pair=(int)blockIdx.x, lvl=pair%3, img=pair/3;
  __shared__ u64 a[2048];
  __shared__ u32 cnt;
  for (int i=threadIdx.x;i<2048;i+=1024) a[i]=0ull;
  if (threadIdx.x==0) cnt=0;
  __syncthreads();
  const u32 T22 = thr[pair*8+2];
  const size_t poff = (size_t)img*131072u + POFFof(lvl);
  const u32 pc = min(pcnt[pair], CAPof(lvl));
  for (u32 i=threadIdx.x; i<pc; i+=1024){
    u64 k = pool[poff+i];
    if ((u32)(k>>42) >= T22){
      u32 id = atomicAdd(&cnt,1u);
      if (id < 2048u) a[id]=k;
    }
  }
  __syncthreads();
  const u32 n = min(cnt, 2048u);
  for (int k=2;k<=2048;k<<=1){
    for (int j=k>>1;j>0;j>>=1){
      for (int t=threadIdx.x;t<2048;t+=1024){
        int ix = t ^ j;
        if (ix > t){
          u64 x=a[t], y=a[ix];
          bool up = ((t & k)==0);
          if (up ? (x<y) : (x>y)){ a[t]=y; a[ix]=x; }
        }
      }
      __syncthreads();
    }
  }
  u32 KK = thr[pair*8+3];
  u32 m = KK < n ? KK : n;
  for (u32 r=threadIdx.x;r<m;r+=1024) sorted[(size_t)pair*1024+r]=a[r];
  if (threadIdx.x==0) thr[pair*8+3]=m;
}

// ---------------- K5: 3-way stable merge + box decode (+ class array) --------
__global__ void merge_kernel(Ptrs p, const u32* thr, const u64* sorted,
                             float* merged, float* clsarr, u32* mcnt){
#pragma clang fp contract(off)
  const int img = blockIdx.x;
  __shared__ u64 mk[3][1024];
  __shared__ int n[3];
  if (threadIdx.x < 3) n[threadIdx.x] = (int)thr[(img*3+threadIdx.x)*8+3];
  __syncthreads();
  const int n0=n[0], n1=n[1], n2=n[2];
  for (int idx=threadIdx.x; idx<3*1024; idx+=blockDim.x){
    int l = idx>>10, r = idx&1023;
    if (r < n[l]){
      u64 key = sorted[(size_t)(img*3+l)*1024 + r];
      mk[l][r] = (key & 0xFFFFFFFF00000000ull) |
                 (u64)(0xFFFFFFFFu - (u32)(l*PRE_K + r));  // concat-idx tie-break
    }
  }
  __syncthreads();
  const int T = n0+n1+n2;
  if (threadIdx.x==0) mcnt[img] = (u32)T;
  for (int t=threadIdx.x; t<T; t+=blockDim.x){
    int l, r;
    if (t < n0){ l=0; r=t; }
    else if (t < n0+n1){ l=1; r=t-n0; }
    else { l=2; r=t-n0-n1; }
    u64 x = mk[l][r];
    int pos = r;
    #pragma unroll
    for (int o=0;o<3;++o) if (o!=l){
      int lo=0, hi=n[o];
      while (lo<hi){ int m=(lo+hi)>>1; if (mk[o][m] > x) lo=m+1; else hi=m; }
      pos += lo;
    }
    u64 key = sorted[(size_t)(img*3+l)*1024 + r];
    u32 flat = 0xFFFFFFFFu - (u32)(key & 0xFFFFFFFFull);
    float score = __uint_as_float((u32)(key>>32));
    int HW = HWof(l);
    int loc = (int)(flat / (u32)NCLS);
    int cls = (int)(flat - (u32)loc*NCLS);
    float lx = p.locs[l][2*loc], ly = p.locs[l][2*loc+1];
    float st = STRof(l);
    const float* rg = p.reg[l] + (size_t)img*4*HW + loc;
    float r0 = rg[0]*st, r1 = rg[HW]*st, r2 = rg[2*(size_t)HW]*st, r3 = rg[3*(size_t)HW]*st;
    float x1 = fminf(fmaxf(lx - r0, 0.f), 1216.f);
    float y1 = fminf(fmaxf(ly - r1, 0.f),  800.f);
    float x2 = fminf(fmaxf(lx + r2, 0.f), 1216.f);
    float y2 = fminf(fmaxf(ly + r3, 0.f),  800.f);
    float* out = merged + (size_t)(img*3072 + pos)*8;
    out[0]=x1; out[1]=y1; out[2]=x2; out[3]=y2;
    out[4]=score; out[5]=(float)cls; out[6]=(float)l; out[7]=(float)loc;
    clsarr[img*3072 + pos] = (float)cls;
  }
}

// ---------------- K6a: per-class greedy NMS (640 independent tasks) ----------
// Class-offset boxes of different classes never overlap (offset 1217 >= image
// diagonal), so the reference's global greedy decomposes exactly into 80
// independent per-class greedies. One 64-thread block per (class,img); boxes
// live in registers; greedy inner loop = ffs+shfl+IoU+ballot (no LDS/barriers).
// Keep flags -> global bitmask. IoU expression identical to validated kernel.
__global__ __launch_bounds__(64)
void nms_class(const float* merged_all, const float* clsarr, const u32* mcnt, u64* gkeep){
#pragma clang fp contract(off)
  const int c = (int)blockIdx.x, img = (int)blockIdx.y;
  const float* merged = merged_all + (size_t)img*3072*8;
  const float* carr = clsarr + (size_t)img*3072;
  const int T = (int)mcnt[img];
  const int lane = (int)threadIdx.x;
  __shared__ unsigned short mlist[3072];
  __shared__ float4 kbox[1024];

  // prefetch class ids (48 independent coalesced loads)
  float fv[48];
  #pragma unroll
  for (int w=0; w<48; ++w){
    int j = w*64 + lane;
    fv[w] = (j < T) ? carr[j] : -1.0f;
  }
  // ballot-compact member indices (ascending = score order)
  int base = 0;
  const u64 lanemask = (lane==0) ? 0ull : ((~0ull) >> (64-lane));
  #pragma unroll
  for (int w=0; w<48; ++w){
    bool mem = ((int)fv[w] == c);
    u64 word = __ballot(mem);
    if (mem){
      int rank = base + (int)__popcll(word & lanemask);
      mlist[rank] = (unsigned short)(w*64 + lane);
    }
    base += (int)__popcll(word);
  }
  const int n = base;
  if (n == 0) return;
  __syncthreads();

  const float off = (float)c * 1217.0f;
  int kc = 0;
  for (int t0 = 0; t0 < n; t0 += 64){
    int r = t0 + lane;
    bool valid = (r < n);
    float4 bx = make_float4(0.f,0.f,0.f,0.f);
    int gj = 0;
    if (valid){
      gj = (int)mlist[r];
      const float* rec = merged + (size_t)gj*8;
      bx = make_float4(rec[0]+off, rec[1]+off, rec[2]+off, rec[3]+off);
    }
    float ax = (bx.z-bx.x)*(bx.w-bx.y);
    bool alive_l = valid;
    // suppression by kept boxes of earlier tiles
    for (int q=0; q<kc; ++q){
      float4 bq = kbox[q];
      float aq = (bq.z-bq.x)*(bq.w-bq.y);
      float ltx=fmaxf(bq.x,bx.x), lty=fmaxf(bq.y,bx.y);
      float rbx=fminf(bq.z,bx.z), rby=fminf(bq.w,bx.w);
      float wx=fmaxf(rbx-ltx,0.f), wy=fmaxf(rby-lty,0.f);
      float inter=wx*wy;
      float denom=aq+ax; denom=denom-inter; denom=denom+1e-9f;
      if (alive_l && (inter/denom > 0.6f)) alive_l=false;
    }
    u64 alive = __ballot(alive_l);
    // intra-tile greedy, registers only
    while (alive){
      int i = __ffsll((unsigned long long)alive) - 1;
      float bix=__shfl(bx.x,i), biy=__shfl(bx.y,i), biz=__shfl(bx.z,i), biw=__shfl(bx.w,i);
      int gi = __shfl(gj, i);
      if (lane==0){
        atomicOr((unsigned long long*)&gkeep[img*48 + (gi>>6)], 1ull<<(gi&63));
        if (kc < 1024) kbox[kc] = make_float4(bix,biy,biz,biw);
      }
      kc++;
      float ai=(biz-bix)*(biw-biy);
      float ltx=fmaxf(bix,bx.x), lty=fmaxf(biy,bx.y);
      float rbx=fminf(biz,bx.z), rby=fminf(biw,bx.w);
      float wx=fmaxf(rbx-ltx,0.f), wy=fmaxf(rby-lty,0.f);
      float inter=wx*wy;
      float denom=ai+ax; denom=denom-inter; denom=denom+1e-9f;
      bool supp = alive_l && (inter/denom > 0.6f);   // lane i: IoU=1 -> self-cleared
      u64 killm = __ballot(supp);
      alive &= ~killm;
      alive &= ~(1ull<<i);
      alive_l = alive_l && !supp;
    }
    __syncthreads();   // kbox visible before next tile
  }
}

// ---------------- K6b: extract first 100 kept + write outputs ----------------
__global__ __launch_bounds__(256)
void emit_kernel(Ptrs p, const float* merged_all, const u64* gkeep, float* out){
  const int img = (int)blockIdx.x;
  const float* merged = merged_all + (size_t)img*3072*8;
  __shared__ unsigned short klist[128];
  __shared__ int skept;
  const int tid = (int)threadIdx.x;
  if (tid < 64){
    int base = 0;
    for (int w=0; w<48 && base<POST_K; ++w){
      u64 word = gkeep[img*48+w];
      int cnt = (int)__popcll(word);
      if (tid < cnt && base+tid < POST_K){
        u64 x = word;
        for (int k=0;k<tid;++k) x &= x-1ull;
        klist[base+tid] = (unsigned short)(w*64 + (__ffsll((unsigned long long)x)-1));
      }
      base += cnt;
    }
    if (tid==0) skept = base < POST_K ? base : POST_K;
  }
  __syncthreads();
  const int kept = skept;

  // ---- outputs: boxes[8][100][4] | scores[8][100] | cls[8][100] | cofs[8][100][128] | kv[8][100]
  float* obx = out;
  float* osc = out + 3200;
  float* ocl = out + 4000;
  float* ocf = out + 4800;
  float* okv = out + 107200;
  for (int r=tid; r<POST_K; r+=256){
    if (r < kept){
      int i = klist[r];
      const float* rec = merged + (size_t)i*8;
      obx[(img*POST_K+r)*4+0]=rec[0];
      obx[(img*POST_K+r)*4+1]=rec[1];
      obx[(img*POST_K+r)*4+2]=rec[2];
      obx[(img*POST_K+r)*4+3]=rec[3];
      osc[img*POST_K+r] = sqrtf(fmaxf(rec[4], 1e-12f));
      ocl[img*POST_K+r] = rec[5];
      okv[img*POST_K+r] = 1.0f;
    } else {
      obx[(img*POST_K+r)*4+0]=0.f;
      obx[(img*POST_K+r)*4+1]=0.f;
      obx[(img*POST_K+r)*4+2]=0.f;
      obx[(img*POST_K+r)*4+3]=0.f;
      osc[img*POST_K+r] = 0.f;
      ocl[img*POST_K+r] = -1.0f;
      okv[img*POST_K+r] = 0.f;
    }
  }
  for (int q=tid; q<POST_K*128; q+=256){
    int r = q>>7, d = q&127;
    float v = 0.f;
    if (r < kept){
      int i = klist[r];
      const float* rec = merged + (size_t)i*8;
      int l = (int)rec[6]; int loc = (int)rec[7];
      int HW = HWof(l);
      v = p.cofs[l][((size_t)img*128 + d)*HW + loc];
    }
    ocf[(img*POST_K+r)*128 + d] = v;
  }
}

// ---------------- host ----------------
extern "C" void kernel_launch(void* const* d_in, const int* in_sizes, int n_in,
                              void* d_out, int out_size, void* d_ws, size_t ws_size,
                              hipStream_t stream){
  Ptrs p;
  for (int l=0; l<3; ++l){
    p.locs[l]   = (const float*)d_in[5*l+0];
    p.logits[l] = (const float*)d_in[5*l+1];
    p.reg[l]    = (const float*)d_in[5*l+2];
    p.ctr[l]    = (const float*)d_in[5*l+3];
    p.cofs[l]   = (const float*)d_in[5*l+4];
  }
  char* ws = (char*)d_ws;
  u32* hist1  = (u32*)(ws + OFF_HIST1);
  u32* cand   = (u32*)(ws + OFF_CAND);
  u32* pcnt   = (u32*)(ws + OFF_PCNT);
  u32* thr    = (u32*)(ws + OFF_THR);
  u32* mcnt   = (u32*)(ws + OFF_MCNT);
  u64* gkeep  = (u64*)(ws + OFF_KEEP);
  float* sctr = (float*)(ws + OFF_SCTR);
  u64* pool   = (u64*)(ws + OFF_POOL);
  float* clsarr = (float*)(ws + OFF_POOL);      // reuses dead pool space
  u64* sorted = (u64*)(ws + OFF_SORT);
  float* merged = (float*)(ws + OFF_MERG);

  hipMemsetAsync(ws, 0, ZERO_BYTES, stream);
  sctr_kernel<<<dim3(78,8), 256, 0, stream>>>(p, sctr);
  fused_pass<<<dim3(NBALL,8), 256, 0, stream>>>(p, sctr, cand, pcnt, pool);
  fb_hist<<<dim3(NBALL,8), 256, 0, stream>>>(p, sctr, cand, pcnt, hist1);     // no-op when pool suffices
  selA<<<24, 256, 0, stream>>>(cand, pcnt, thr, hist1, pool);
  refill_pass<<<dim3(NBALL,8), 256, 0, stream>>>(p, sctr, cand, pcnt, thr, pool); // no-op when pool suffices
  selB<<<24, 256, 0, stream>>>(thr, pcnt, pool);
  sort_pool<<<24, 1024, 0, stream>>>(thr, pcnt, pool, sorted);
  merge_kernel<<<8, 1024, 0, stream>>>(p, thr, sorted, merged, clsarr, mcnt);
  nms_class<<<dim3(NCLS,8), 64, 0, stream>>>(merged, clsarr, mcnt, gkeep);
  emit_kernel<<<8, 256, 0, stream>>>(p, merged, gkeep, (float*)d_out);
}

// Round 9
// 192.426 us; speedup vs baseline: 1.4708x; 1.2109x over previous
//
#include <hip/hip_runtime.h>

typedef unsigned int u32;
typedef unsigned long long u64;

// ---------------- problem constants ----------------
#define NCLS 80
#define NIMG 8
#define PRE_K 1000
#define POST_K 100
// HW: 15200, 3800, 950 ; strides 8,16,32 ; concat bases 0,15200,19000
#define SCTR_STRIDE 19952
#define PBUF_N 2048

__device__ __forceinline__ int HWof(int l){ return l==0?15200:(l==1?3800:950); }
__device__ __forceinline__ float STRof(int l){ return l==0?8.f:(l==1?16.f:32.f); }
// pool caps / per-image offsets (u64 indices); stride per img = 131072 keys
__device__ __forceinline__ u32 CAPof(int l){ return l==0?65536u:32768u; }
__device__ __forceinline__ u32 POFFof(int l){ return l==0?0u:(l==1?65536u:98304u); }

struct Ptrs {
  const float* logits[3];
  const float* reg[3];
  const float* ctr[3];
  const float* cofs[3];
  const float* locs[3];
};

// grid split: 149 lvl0-tiles, 38 lvl1, 10 lvl2 (2048 float4 per tile)
#define NB0 149
#define NB1 38
#define NBALL 197

// ---------------- workspace layout (bytes) ----------------
// zeroed every launch:
#define OFF_HIST1 0u            // 24*512*4 = 49152 (fallback only)
#define OFF_CAND  49152u        // 24*4
#define OFF_PCNT  49248u        // 24*4
#define OFF_THR   49344u        // 24*8*4 = 768 {B1, cntAbove, T22, n_l, ok, -,-,-}
#define OFF_MCNT  50112u        // 32
#define OFF_KEEP  50144u        // 8*48*8 = 3072 keep bitmask per image
#define ZERO_BYTES 53216u
// not zeroed:
#define OFF_KLIST 53248u        // 8*100*4 = 3200 packed (l<<16)|loc per kept row
#define OFF_SCTR  56448u        // 8*19952*4 = 638464
#define OFF_POOL  694912u       // 8*131072*8 = 8388608  (dead after sort_pool;
                                //  first 98304B reused as clsarr by merge)
#define OFF_SORT  9083520u      // 24*1024*8 = 196608
#define OFF_MERG  9280128u      // 8*3072*8*4 = 786432   (total ~10.07 MB)

__device__ __forceinline__ float sigmoidf(float x){ return 1.0f/(1.0f+expf(-x)); }

// ---------------- K0: sigmoid(ctr) for all (img, concat-loc) ----------------
__global__ void sctr_kernel(Ptrs p, float* sctr){
  int img = blockIdx.y;
  int i = blockIdx.x*256 + threadIdx.x;
  if (i >= 19950) return;
  int l, loc;
  if (i < 15200){ l=0; loc=i; }
  else if (i < 19000){ l=1; loc=i-15200; }
  else { l=2; loc=i-19000; }
  int HW = HWof(l);
  float x = p.ctr[l][(size_t)img*HW + loc];
  sctr[img*SCTR_STRIDE + i] = sigmoidf(x);
}

// ---------------- streaming pass body -----------------------------------
template<int LVL, bool REFILL>
__device__ __forceinline__ void pass_body(int tile, int img, const Ptrs& p, const float* sctr,
                                          u32* cand, u32* pcnt, const u32* thr, u64* pool,
                                          u64* pbuf, u32* shctl){
  constexpr int HW   = LVL==0?15200:(LVL==1?3800:950);
  constexpr int BASE = LVL==0?0:(LVL==1?15200:19000);
  constexpr int NE   = 80*HW;
  constexpr int NF4  = NE/4;
  const u32 CAP = CAPof(LVL);
  const int pair = img*3 + LVL;
  const size_t poff = (size_t)img*131072u + POFFof(LVL);
  // static floors: score >= {0.3125, 0.25, 0.125}
  const u32 tbin = REFILL ? thr[pair*8+0] : (LVL==0?501u:(LVL==1?500u:496u));
  const float4* plane = (const float4*)(p.logits[LVL] + (size_t)img*NE);
  const float* sc = sctr + img*SCTR_STRIDE + BASE;
  if (threadIdx.x==0){ shctl[0]=0; shctl[1]=0; }
  __syncthreads();
  u32 mc = 0;
  #pragma unroll
  for (int k=0;k<8;++k){
    int f4 = tile*2048 + k*256 + (int)threadIdx.x;
    if (f4 < NF4){
      float4 v = plane[f4];
      int e0 = f4*4;
      int cls0 = e0 / HW;
      int loc0 = e0 - cls0*HW;
      float ss[4];
      if (LVL==2){                        // HW=950 not %4: rows can split a float4
        #pragma unroll
        for (int j=0;j<4;++j){ int e=e0+j; int c=e/HW; ss[j]=sc[e-c*HW]; }
      } else {
        float4 s4 = *(const float4*)(sc + loc0);
        ss[0]=s4.x; ss[1]=s4.y; ss[2]=s4.z; ss[3]=s4.w;
      }
      float vv[4] = {v.x,v.y,v.z,v.w};
      #pragma unroll
      for (int j=0;j<4;++j){
        float sl = sigmoidf(vv[j]);
        if (sl > 0.05f){
          if (!REFILL) mc++;
          u32 bits = __float_as_uint(sl * ss[j]);
          if ((bits>>21) >= tbin){
            int e = e0 + j, cls, loc;
            if (LVL==2){ cls=e/HW; loc=e-cls*HW; } else { cls=cls0; loc=loc0+j; }
            u64 key = ((u64)bits<<32) | (u64)(0xFFFFFFFFu - (u32)(loc*NCLS + cls));
            u32 id = atomicAdd(&shctl[0], 1u);
            if (id < (u32)PBUF_N) pbuf[id] = key;
            else { u32 g = atomicAdd(&pcnt[pair],1u); if (g<CAP) pool[poff+g]=key; }
          }
        }
      }
    }
  }
  if (!REFILL && mc) atomicAdd(&shctl[1], mc);
  __syncthreads();
  u32 m = shctl[0]; if (m > (u32)PBUF_N) m = PBUF_N;
  if (threadIdx.x==0){
    if (m) shctl[2] = atomicAdd(&pcnt[pair], m);
    if (!REFILL && shctl[1]) atomicAdd(&cand[pair], shctl[1]);
  }
  __syncthreads();
  for (u32 i=threadIdx.x; i<m; i+=256){
    u32 d = shctl[2] + i;
    if (d < CAP) pool[poff+d] = pbuf[i];
  }
}

// ---------------- K1: THE single full-data pass ----------------
__global__ __launch_bounds__(256)
void fused_pass(Ptrs p, const float* sctr, u32* cand, u32* pcnt, u64* pool){
  __shared__ u64 pbuf[PBUF_N];
  __shared__ u32 shctl[4];
  const int bx=(int)blockIdx.x, img=(int)blockIdx.y;
  if (bx<NB0)          pass_body<0,false>(bx,        img,p,sctr,cand,pcnt,nullptr,pool,pbuf,shctl);
  else if (bx<NB0+NB1) pass_body<1,false>(bx-NB0,    img,p,sctr,cand,pcnt,nullptr,pool,pbuf,shctl);
  else                 pass_body<2,false>(bx-NB0-NB1,img,p,sctr,cand,pcnt,nullptr,pool,pbuf,shctl);
}

// ---------------- fallback: full coarse hist (only if pool insufficient) -----
template<int LVL>
__device__ __forceinline__ void fbhist_body(int tile, int img, const Ptrs& p,
                                            const float* sctr, u32* lh){
  constexpr int HW   = LVL==0?15200:(LVL==1?3800:950);
  constexpr int BASE = LVL==0?0:(LVL==1?15200:19000);
  constexpr int NE   = 80*HW;
  constexpr int NF4  = NE/4;
  const float4* plane = (const float4*)(p.logits[LVL] + (size_t)img*NE);
  const float* sc = sctr + img*SCTR_STRIDE + BASE;
  #pragma unroll
  for (int k=0;k<8;++k){
    int f4 = tile*2048 + k*256 + (int)threadIdx.x;
    if (f4 < NF4){
      float4 v = plane[f4];
      int e0 = f4*4;
      int cls0 = e0 / HW;
      int loc0 = e0 - cls0*HW;
      float ss[4];
      if (LVL==2){
        #pragma unroll
        for (int j=0;j<4;++j){ int e=e0+j; int c=e/HW; ss[j]=sc[e-c*HW]; }
      } else {
        float4 s4 = *(const float4*)(sc + loc0);
        ss[0]=s4.x; ss[1]=s4.y; ss[2]=s4.z; ss[3]=s4.w;
      }
      float vv[4] = {v.x,v.y,v.z,v.w};
      #pragma unroll
      for (int j=0;j<4;++j){
        float sl = sigmoidf(vv[j]);
        if (sl > 0.05f){
          u32 bits = __float_as_uint(sl * ss[j]);
          atomicAdd(&lh[bits>>21], 1u);
        }
      }
    }
  }
}

__global__ __launch_bounds__(256)
void fb_hist(Ptrs p, const float* sctr, const u32* cand, const u32* pcnt, u32* hist1){
  __shared__ u32 lh[512];
  const int bx=(int)blockIdx.x, img=(int)blockIdx.y;
  const int lvl = bx<NB0?0:(bx<NB0+NB1?1:2);
  const int pair = img*3+lvl;
  u32 pc = pcnt[pair], kk = min(cand[pair], (u32)PRE_K);
  if (pc <= CAPof(lvl) && pc >= kk) return;     // pool sufficient -> no fallback
  for (int b=threadIdx.x;b<512;b+=256) lh[b]=0;
  __syncthreads();
  if (lvl==0)      fbhist_body<0>(bx,        img,p,sctr,lh);
  else if (lvl==1) fbhist_body<1>(bx-NB0,    img,p,sctr,lh);
  else             fbhist_body<2>(bx-NB0-NB1,img,p,sctr,lh);
  __syncthreads();
  for (int b=threadIdx.x;b<512;b+=256) if (lh[b]) atomicAdd(&hist1[pair*512+b], lh[b]);
}

// ---------------- K2: coarse select (hist from pool OR fallback hist) + scan --
__global__ __launch_bounds__(256)
void selA(const u32* cand, u32* pcnt, u32* thr, const u32* hist1, const u64* pool){
  const int pair=(int)blockIdx.x, lvl=pair%3, img=pair/3;
  __shared__ u32 h[512], seg[256], excl[256];
  const u32 cap = CAPof(lvl);
  const size_t poff = (size_t)img*131072u + POFFof(lvl);
  u32 pc = pcnt[pair];
  u32 kk = min(cand[pair], (u32)PRE_K);
  bool ok = (pc <= cap) && (pc >= kk);
  for (int b=threadIdx.x;b<512;b+=256) h[b] = ok ? 0u : hist1[pair*512+b];
  __syncthreads();
  if (ok){
    for (u32 i=threadIdx.x; i<pc; i+=256)
      atomicAdd(&h[(u32)(pool[poff+i]>>53)], 1u);
  }
  __syncthreads();
  if (threadIdx.x==0){
    thr[pair*8+3] = kk;
    thr[pair*8+4] = ok ? 1u : 0u;
    if (!ok) pcnt[pair] = 0;                    // refill_pass will repopulate
    if (kk==0){ thr[pair*8+0]=0xFFFFu; thr[pair*8+2]=0xFFFFFFFFu; }
  }
  if (kk==0) return;
  // descending scan over 512 bins (2 per thread)
  const int t = threadIdx.x;
  u32 part = h[511-2*t] + h[511-(2*t+1)];
  seg[t]=part;
  __syncthreads();
  if (t==0){ u32 run=0; for (int i=0;i<256;++i){ excl[i]=run; run+=seg[i]; } }
  __syncthreads();
  u32 cum = excl[t];
  #pragma unroll
  for (int k=0;k<2;++k){
    int bin = 511-(2*t+k);
    u32 c = h[bin];
    if (c && cum < kk && cum + c >= kk){ thr[pair*8+0]=(u32)bin; thr[pair*8+1]=cum; }
    cum += c;
  }
}

// ---------------- fallback: exact refill of pool with bin >= B1 --------------
__global__ __launch_bounds__(256)
void refill_pass(Ptrs p, const float* sctr, u32* cand, u32* pcnt, const u32* thr, u64* pool){
  __shared__ u64 pbuf[PBUF_N];
  __shared__ u32 shctl[4];
  const int bx=(int)blockIdx.x, img=(int)blockIdx.y;
  const int lvl = bx<NB0?0:(bx<NB0+NB1?1:2);
  if (thr[(img*3+lvl)*8+4]) return;             // pool was sufficient
  if (lvl==0)      pass_body<0,true>(bx,        img,p,sctr,cand,pcnt,thr,pool,pbuf,shctl);
  else if (lvl==1) pass_body<1,true>(bx-NB0,    img,p,sctr,cand,pcnt,thr,pool,pbuf,shctl);
  else             pass_body<2,true>(bx-NB0-NB1,img,p,sctr,cand,pcnt,thr,pool,pbuf,shctl);
}

// ---------------- K3: fine select within boundary bin (from pool) + scan -----
__global__ __launch_bounds__(256)
void selB(u32* thr, const u32* pcnt, const u64* pool){
  const int pair=(int)blockIdx.x, lvl=pair%3, img=pair/3;
  const u32 kk = thr[pair*8+3];
  if (kk==0) return;                            // T22 already 0xFFFFFFFF
  const u32 B1 = thr[pair*8+0];
  const u32 KK = kk - thr[pair*8+1];            // remaining within boundary bin
  __shared__ u32 h[2048], seg[256], excl[256];
  for (int b=threadIdx.x;b<2048;b+=256) h[b]=0;
  __syncthreads();
  const size_t poff = (size_t)img*131072u + POFFof(lvl);
  const u32 pc = min(pcnt[pair], CAPof(lvl));
  for (u32 i=threadIdx.x; i<pc; i+=256){
    u64 key = pool[poff+i];
    if ((u32)(key>>53) == B1) atomicAdd(&h[(u32)(key>>42)&0x7FFu], 1u);
  }
  __syncthreads();
  const int t = threadIdx.x;
  u32 part = 0;
  #pragma unroll
  for (int k=0;k<8;++k) part += h[2047-(t*8+k)];
  seg[t]=part;
  __syncthreads();
  if (t==0){ u32 run=0; for (int i=0;i<256;++i){ excl[i]=run; run+=seg[i]; } }
  __syncthreads();
  u32 cum = excl[t];
  #pragma unroll
  for (int k=0;k<8;++k){
    int bin = 2047-(t*8+k);
    u32 c = h[bin];
    if (c && cum < KK && cum + c >= KK) thr[pair*8+2] = (B1<<11) | (u32)bin;
    cum += c;
  }
}

// ---------------- K4: gather accepted keys from pool, bitonic sort, top n_l --
__global__ __launch_bounds__(1024)
void sort_pool(u32* thr, const u32* pcnt, const u64* pool, u64* sorted){
  const int pair=(int)blockIdx.x, lvl=pair%3, img=pair/3;
  __shared__ u64 a[2048];
  __shared__ u32 cnt;
  for (int i=threadIdx.x;i<2048;i+=1024) a[i]=0ull;
  if (threadIdx.x==0) cnt=0;
  __syncthreads();
  const u32 T22 = thr[pair*8+2];
  const size_t poff = (size_t)img*131072u + POFFof(lvl);
  const u32 pc = min(pcnt[pair], CAPof(lvl));
  for (u32 i=threadIdx.x; i<pc; i+=1024){
    u64 k = pool[poff+i];
    if ((u32)(k>>42) >= T22){
      u32 id = atomicAdd(&cnt,1u);
      if (id < 2048u) a[id]=k;
    }
  }
  __syncthreads();
  const u32 n = min(cnt, 2048u);
  for (int k=2;k<=2048;k<<=1){
    for (int j=k>>1;j>0;j>>=1){
      for (int t=threadIdx.x;t<2048;t+=1024){
        int ix = t ^ j;
        if (ix > t){
          u64 x=a[t], y=a[ix];
          bool up = ((t & k)==0);
          if (up ? (x<y) : (x>y)){ a[t]=y; a[ix]=x; }
        }
      }
      __syncthreads();
    }
  }
  u32 KK = thr[pair*8+3];
  u32 m = KK < n ? KK : n;
  for (u32 r=threadIdx.x;r<m;r+=1024) sorted[(size_t)pair*1024+r]=a[r];
  if (threadIdx.x==0) thr[pair*8+3]=m;
}

// ---------------- K5: 3-way stable merge + box decode (+ class array) --------
__global__ void merge_kernel(Ptrs p, const u32* thr, const u64* sorted,
                             float* merged, float* clsarr, u32* mcnt){
#pragma clang fp contract(off)
  const int img = blockIdx.x;
  __shared__ u64 mk[3][1024];
  __shared__ int n[3];
  if (threadIdx.x < 3) n[threadIdx.x] = (int)thr[(img*3+threadIdx.x)*8+3];
  __syncthreads();
  const int n0=n[0], n1=n[1], n2=n[2];
  for (int idx=threadIdx.x; idx<3*1024; idx+=blockDim.x){
    int l = idx>>10, r = idx&1023;
    if (r < n[l]){
      u64 key = sorted[(size_t)(img*3+l)*1024 + r];
      mk[l][r] = (key & 0xFFFFFFFF00000000ull) |
                 (u64)(0xFFFFFFFFu - (u32)(l*PRE_K + r));  // concat-idx tie-break
    }
  }
  __syncthreads();
  const int T = n0+n1+n2;
  if (threadIdx.x==0) mcnt[img] = (u32)T;
  for (int t=threadIdx.x; t<T; t+=blockDim.x){
    int l, r;
    if (t < n0){ l=0; r=t; }
    else if (t < n0+n1){ l=1; r=t-n0; }
    else { l=2; r=t-n0-n1; }
    u64 x = mk[l][r];
    int pos = r;
    #pragma unroll
    for (int o=0;o<3;++o) if (o!=l){
      int lo=0, hi=n[o];
      while (lo<hi){ int m=(lo+hi)>>1; if (mk[o][m] > x) lo=m+1; else hi=m; }
      pos += lo;
    }
    u64 key = sorted[(size_t)(img*3+l)*1024 + r];
    u32 flat = 0xFFFFFFFFu - (u32)(key & 0xFFFFFFFFull);
    float score = __uint_as_float((u32)(key>>32));
    int HW = HWof(l);
    int loc = (int)(flat / (u32)NCLS);
    int cls = (int)(flat - (u32)loc*NCLS);
    float lx = p.locs[l][2*loc], ly = p.locs[l][2*loc+1];
    float st = STRof(l);
    const float* rg = p.reg[l] + (size_t)img*4*HW + loc;
    float r0 = rg[0]*st, r1 = rg[HW]*st, r2 = rg[2*(size_t)HW]*st, r3 = rg[3*(size_t)HW]*st;
    float x1 = fminf(fmaxf(lx - r0, 0.f), 1216.f);
    float y1 = fminf(fmaxf(ly - r1, 0.f),  800.f);
    float x2 = fminf(fmaxf(lx + r2, 0.f), 1216.f);
    float y2 = fminf(fmaxf(ly + r3, 0.f),  800.f);
    float* out = merged + (size_t)(img*3072 + pos)*8;
    out[0]=x1; out[1]=y1; out[2]=x2; out[3]=y2;
    out[4]=score; out[5]=(float)cls; out[6]=(float)l; out[7]=(float)loc;
    clsarr[img*3072 + pos] = (float)cls;
  }
}

// ---------------- K6a: per-class greedy NMS (640 independent tasks) ----------
__global__ __launch_bounds__(64)
void nms_class(const float* merged_all, const float* clsarr, const u32* mcnt, u64* gkeep){
#pragma clang fp contract(off)
  const int c = (int)blockIdx.x, img = (int)blockIdx.y;
  const float* merged = merged_all + (size_t)img*3072*8;
  const float* carr = clsarr + (size_t)img*3072;
  const int T = (int)mcnt[img];
  const int lane = (int)threadIdx.x;
  __shared__ unsigned short mlist[3072];
  __shared__ float4 kbox[1024];

  // prefetch class ids (48 independent coalesced loads)
  float fv[48];
  #pragma unroll
  for (int w=0; w<48; ++w){
    int j = w*64 + lane;
    fv[w] = (j < T) ? carr[j] : -1.0f;
  }
  // ballot-compact member indices (ascending = score order)
  int base = 0;
  const u64 lanemask = (lane==0) ? 0ull : ((~0ull) >> (64-lane));
  #pragma unroll
  for (int w=0; w<48; ++w){
    bool mem = ((int)fv[w] == c);
    u64 word = __ballot(mem);
    if (mem){
      int rank = base + (int)__popcll(word & lanemask);
      mlist[rank] = (unsigned short)(w*64 + lane);
    }
    base += (int)__popcll(word);
  }
  const int n = base;
  if (n == 0) return;
  __syncthreads();

  const float off = (float)c * 1217.0f;
  int kc = 0;
  for (int t0 = 0; t0 < n; t0 += 64){
    int r = t0 + lane;
    bool valid = (r < n);
    float4 bx = make_float4(0.f,0.f,0.f,0.f);
    int gj = 0;
    if (valid){
      gj = (int)mlist[r];
      const float* rec = merged + (size_t)gj*8;
      bx = make_float4(rec[0]+off, rec[1]+off, rec[2]+off, rec[3]+off);
    }
    float ax = (bx.z-bx.x)*(bx.w-bx.y);
    bool alive_l = valid;
    // suppression by kept boxes of earlier tiles
    for (int q=0; q<kc; ++q){
      float4 bq = kbox[q];
      float aq = (bq.z-bq.x)*(bq.w-bq.y);
      float ltx=fmaxf(bq.x,bx.x), lty=fmaxf(bq.y,bx.y);
      float rbx=fminf(bq.z,bx.z), rby=fminf(bq.w,bx.w);
      float wx=fmaxf(rbx-ltx,0.f), wy=fmaxf(rby-lty,0.f);
      float inter=wx*wy;
      float denom=aq+ax; denom=denom-inter; denom=denom+1e-9f;
      if (alive_l && (inter/denom > 0.6f)) alive_l=false;
    }
    u64 alive = __ballot(alive_l);
    // intra-tile greedy, registers only
    while (alive){
      int i = __ffsll((unsigned long long)alive) - 1;
      float bix=__shfl(bx.x,i), biy=__shfl(bx.y,i), biz=__shfl(bx.z,i), biw=__shfl(bx.w,i);
      int gi = __shfl(gj, i);
      if (lane==0){
        atomicOr((unsigned long long*)&gkeep[img*48 + (gi>>6)], 1ull<<(gi&63));
        if (kc < 1024) kbox[kc] = make_float4(bix,biy,biz,biw);
      }
      kc++;
      float ai=(biz-bix)*(biw-biy);
      float ltx=fmaxf(bix,bx.x), lty=fmaxf(biy,bx.y);
      float rbx=fminf(biz,bx.z), rby=fminf(biw,bx.w);
      float wx=fmaxf(rbx-ltx,0.f), wy=fmaxf(rby-lty,0.f);
      float inter=wx*wy;
      float denom=ai+ax; denom=denom-inter; denom=denom+1e-9f;
      bool supp = alive_l && (inter/denom > 0.6f);   // lane i: IoU=1 -> self-cleared
      u64 killm = __ballot(supp);
      alive &= ~killm;
      alive &= ~(1ull<<i);
      alive_l = alive_l && !supp;
    }
    __syncthreads();   // kbox visible before next tile
  }
}

// ---------------- K6b: extract first 100 kept + write meta outputs -----------
__global__ __launch_bounds__(256)
void emit_meta(const float* merged_all, const u64* gkeep, u32* klmeta, float* out){
  const int img = (int)blockIdx.x;
  const float* merged = merged_all + (size_t)img*3072*8;
  __shared__ unsigned short klist[128];
  __shared__ int skept;
  const int tid = (int)threadIdx.x;
  if (tid < 64){
    int base = 0;
    for (int w=0; w<48 && base<POST_K; ++w){
      u64 word = gkeep[img*48+w];
      int cnt = (int)__popcll(word);
      if (tid < cnt && base+tid < POST_K){
        u64 x = word;
        for (int k=0;k<tid;++k) x &= x-1ull;
        klist[base+tid] = (unsigned short)(w*64 + (__ffsll((unsigned long long)x)-1));
      }
      base += cnt;
    }
    if (tid==0) skept = base < POST_K ? base : POST_K;
  }
  __syncthreads();
  const int kept = skept;

  float* obx = out;
  float* osc = out + 3200;
  float* ocl = out + 4000;
  float* okv = out + 107200;
  for (int r=tid; r<POST_K; r+=256){
    if (r < kept){
      int i = klist[r];
      const float* rec = merged + (size_t)i*8;
      obx[(img*POST_K+r)*4+0]=rec[0];
      obx[(img*POST_K+r)*4+1]=rec[1];
      obx[(img*POST_K+r)*4+2]=rec[2];
      obx[(img*POST_K+r)*4+3]=rec[3];
      osc[img*POST_K+r] = sqrtf(fmaxf(rec[4], 1e-12f));
      ocl[img*POST_K+r] = rec[5];
      okv[img*POST_K+r] = 1.0f;
      klmeta[img*POST_K+r] = ((u32)rec[6]<<16) | (u32)rec[7];   // (l<<16)|loc
    } else {
      obx[(img*POST_K+r)*4+0]=0.f;
      obx[(img*POST_K+r)*4+1]=0.f;
      obx[(img*POST_K+r)*4+2]=0.f;
      obx[(img*POST_K+r)*4+3]=0.f;
      osc[img*POST_K+r] = 0.f;
      ocl[img*POST_K+r] = -1.0f;
      okv[img*POST_K+r] = 0.f;
      klmeta[img*POST_K+r] = 0xFFFFFFFFu;
    }
  }
}

// ---------------- K6c: cofs gather, one block per kept row (800-way) ---------
__global__ __launch_bounds__(128)
void emit_cofs(Ptrs p, const u32* klmeta, float* out){
  const int r = (int)blockIdx.x, img = (int)blockIdx.y;
  const int d = (int)threadIdx.x;
  const u32 meta = klmeta[img*POST_K + r];
  float v = 0.f;
  if (meta != 0xFFFFFFFFu){
    int l = (int)(meta >> 16), loc = (int)(meta & 0xFFFFu);
    int HW = HWof(l);
    v = p.cofs[l][((size_t)img*128 + d)*HW + loc];
  }
  float* ocf = out + 4800;
  ocf[(img*POST_K + r)*128 + d] = v;
}

// ---------------- host ----------------
extern "C" void kernel_launch(void* const* d_in, const int* in_sizes, int n_in,
                              void* d_out, int out_size, void* d_ws, size_t ws_size,
                              hipStream_t stream){
  Ptrs p;
  for (int l=0; l<3; ++l){
    p.locs[l]   = (const float*)d_in[5*l+0];
    p.logits[l] = (const float*)d_in[5*l+1];
    p.reg[l]    = (const float*)d_in[5*l+2];
    p.ctr[l]    = (const float*)d_in[5*l+3];
    p.cofs[l]   = (const float*)d_in[5*l+4];
  }
  char* ws = (char*)d_ws;
  u32* hist1  = (u32*)(ws + OFF_HIST1);
  u32* cand   = (u32*)(ws + OFF_CAND);
  u32* pcnt   = (u32*)(ws + OFF_PCNT);
  u32* thr    = (u32*)(ws + OFF_THR);
  u32* mcnt   = (u32*)(ws + OFF_MCNT);
  u64* gkeep  = (u64*)(ws + OFF_KEEP);
  u32* klmeta = (u32*)(ws + OFF_KLIST);
  float* sctr = (float*)(ws + OFF_SCTR);
  u64* pool   = (u64*)(ws + OFF_POOL);
  float* clsarr = (float*)(ws + OFF_POOL);      // reuses dead pool space
  u64* sorted = (u64*)(ws + OFF_SORT);
  float* merged = (float*)(ws + OFF_MERG);

  hipMemsetAsync(ws, 0, ZERO_BYTES, stream);
  sctr_kernel<<<dim3(78,8), 256, 0, stream>>>(p, sctr);
  fused_pass<<<dim3(NBALL,8), 256, 0, stream>>>(p, sctr, cand, pcnt, pool);
  fb_hist<<<dim3(NBALL,8), 256, 0, stream>>>(p, sctr, cand, pcnt, hist1);     // no-op when pool suffices
  selA<<<24, 256, 0, stream>>>(cand, pcnt, thr, hist1, pool);
  refill_pass<<<dim3(NBALL,8), 256, 0, stream>>>(p, sctr, cand, pcnt, thr, pool); // no-op when pool suffices
  selB<<<24, 256, 0, stream>>>(thr, pcnt, pool);
  sort_pool<<<24, 1024, 0, stream>>>(thr, pcnt, pool, sorted);
  merge_kernel<<<8, 1024, 0, stream>>>(p, thr, sorted, merged, clsarr, mcnt);
  nms_class<<<dim3(NCLS,8), 64, 0, stream>>>(merged, clsarr, mcnt, gkeep);
  emit_meta<<<8, 256, 0, stream>>>(merged, gkeep, klmeta, (float*)d_out);
  emit_cofs<<<dim3(POST_K,8), 128, 0, stream>>>(p, klmeta, (float*)d_out);
}